// Round 10
// baseline (96.548 us; speedup 1.0000x reference)
//
#include <hip/hip_runtime.h>

#define D 128
#define B 256
#define WMAX 64
#define SPILL_MAX 8192
#define NPART 8      // XCD count on MI355X; blockIdx % 8 ~ XCD (perf heuristic only)
#define CH 1024      // edges per bucket block (pass A) = B*4
#define CH_SHIFT 10

typedef float vfloat4 __attribute__((ext_vector_type(4)));

// ---------------------------------------------------------------------------
// GCN message passing, ELL + bf16-gather + bucketed XCD-local build:
//   prep   : cursor=0, out2=x (NT), xb=bf16(x)
//   bucket : pass A — per 1024-edge block, classify dests into 8 partitions
//            via LDS counters, append (r,c) to dense per-(part,block) buckets.
//   place2 : pass B — group p (one XCD) reads ONLY bucket p (~600KB, NT),
//            cursor atomic + ssrc store stay in that XCD's L2.
//   agg    : 16 lanes/node, 16B uint4 bf16 gathers, x4 unroll, NT ssrc reads;
//            out[c] = bias + dc*( sum_j rsqrt(deg_rj+1)*xb[r_j] + dc*xb[c] )
//   spill edges (deg > WMAX, normally none) folded into agg.
// Fallback (small ws): round-4 CSR-pairs pipeline.
// ---------------------------------------------------------------------------

__device__ __forceinline__ unsigned short f2bf(float f) {   // RTNE f32->bf16
    unsigned u = __float_as_uint(f);
    u = u + 0x7FFFu + ((u >> 16) & 1u);
    return (unsigned short)(u >> 16);
}

__device__ __forceinline__ vfloat4 bf2f4(unsigned lo, unsigned hi) {
    vfloat4 r;
    r.x = __uint_as_float(lo << 16);
    r.y = __uint_as_float(lo & 0xffff0000u);
    r.z = __uint_as_float(hi << 16);
    r.w = __uint_as_float(hi & 0xffff0000u);
    return r;
}

__global__ void k_prep(const float* __restrict__ x, float* __restrict__ out2,
                       uint2* __restrict__ xb, int* __restrict__ cursor,
                       int* __restrict__ spillCnt, int n) {
    int gid = blockIdx.x * blockDim.x + threadIdx.x;
    if (gid == 0) *spillCnt = 0;
    if (gid < n) cursor[gid] = 0;
    if (gid >= n * 32) return;
    vfloat4 xv = reinterpret_cast<const vfloat4*>(x)[gid];
    __builtin_nontemporal_store(xv, reinterpret_cast<vfloat4*>(out2) + gid);
    uint2 b;
    b.x = (unsigned)f2bf(xv.x) | ((unsigned)f2bf(xv.y) << 16);
    b.y = (unsigned)f2bf(xv.z) | ((unsigned)f2bf(xv.w) << 16);
    xb[gid] = b;
}

// Pass A: block b classifies its 1024 edges into 8 partition buckets.
// bkt[p][b][*] is dense (positions from an LDS counter); cnt[b][p] = fill.
// Entries packed as (src << 32) | dst in a long long.
__global__ void k_bucket(const int* __restrict__ row, const int* __restrict__ col,
                         long long* __restrict__ bkt, int* __restrict__ cnt,
                         int e, int n, int nBlocksA) {
    __shared__ int lcnt[NPART];
    int b = blockIdx.x, t = threadIdx.x;
    if (t < NPART) lcnt[t] = 0;
    __syncthreads();

    int base = b * CH + t * 4;
    int rs[4], cs[4];
    bool vec_ok = ((((uintptr_t)row | (uintptr_t)col) & 15) == 0) && (base + 3 < e);
    if (vec_ok) {
        int4 r4 = reinterpret_cast<const int4*>(row)[base >> 2];
        int4 c4 = reinterpret_cast<const int4*>(col)[base >> 2];
        rs[0] = r4.x; rs[1] = r4.y; rs[2] = r4.z; rs[3] = r4.w;
        cs[0] = c4.x; cs[1] = c4.y; cs[2] = c4.z; cs[3] = c4.w;
    } else {
#pragma unroll
        for (int u = 0; u < 4; ++u) {
            int i = base + u;
            rs[u] = (i < e) ? row[i] : -1;
            cs[u] = (i < e) ? col[i] : 0;
        }
    }
#pragma unroll
    for (int u = 0; u < 4; ++u) {
        if (rs[u] < 0) continue;
        int p = (int)((long long)cs[u] * NPART / n);
        if (p > NPART - 1) p = NPART - 1;
        int pos = atomicAdd(&lcnt[p], 1);
        bkt[((size_t)p * nBlocksA + b) * CH + pos] =
            ((long long)rs[u] << 32) | (unsigned)cs[u];
    }
    __syncthreads();
    if (t < NPART) cnt[b * NPART + t] = lcnt[t];
}

// Pass B: group p (blockIdx%8) drains bucket p only. All cursor atomics and
// ssrc stores are XCD-local; bucket reads are dense + nontemporal.
__global__ void k_place2(const long long* __restrict__ bkt, const int* __restrict__ cnt,
                         int* __restrict__ cursor, int* __restrict__ ssrc,
                         int2* __restrict__ spill, int* __restrict__ spillCnt,
                         int nBlocksA) {
    int p  = blockIdx.x & (NPART - 1);
    int bg = blockIdx.x >> 3;
    int tg = bg * blockDim.x + threadIdx.x;
    int T  = (gridDim.x >> 3) * blockDim.x;
    int total = nBlocksA * CH;

    for (int s = tg; s < total; s += T) {
        int b = s >> CH_SHIFT;
        int k = s & (CH - 1);
        int c_ = cnt[b * NPART + p];
        if (k >= c_) continue;
        long long ent = __builtin_nontemporal_load(bkt + ((size_t)p * nBlocksA + b) * CH + k);
        int r_ = (int)(ent >> 32);
        int cdst = (int)(ent & 0xffffffffLL);
        int pos = atomicAdd(&cursor[cdst], 1);
        if (pos < WMAX) {
            ssrc[cdst * WMAX + pos] = r_;
        } else {
            int sl = atomicAdd(spillCnt, 1);
            if (sl < SPILL_MAX) spill[sl] = make_int2(r_, cdst);
        }
    }
}

// 16 lanes per node: each lane loads 16B (8 bf16) of a row; 4 nodes per wave.
// x4 unrolled; ssrc via nontemporal loads; spill folded in.
__global__ void k_agg_ell(const uint2* __restrict__ xb, const float* __restrict__ bias,
                          const int* __restrict__ cursor, const int* __restrict__ ssrc,
                          const int2* __restrict__ spill, const int* __restrict__ spillCnt,
                          float* __restrict__ out, int n) {
    int p  = blockIdx.x & (NPART - 1);
    int bg = blockIdx.x >> 3;
    int lo = (int)((long long)n * p / NPART);
    int hi = (int)((long long)n * (p + 1) / NPART);
    int node = lo + bg * 16 + (threadIdx.x >> 4);     // 16 nodes per block
    if (node >= hi) return;
    int q = threadIdx.x & 15;                          // 16B chunk index

    const uint4* xb4 = reinterpret_cast<const uint4*>(xb);

    int cnt = cursor[node];
    int m   = min(cnt, WMAX);
    const int* sp = ssrc + node * WMAX;

    vfloat4 a0 = {0.f, 0.f, 0.f, 0.f};
    vfloat4 a1 = a0, a2 = a0, a3 = a0;           // low half (dims q*8..q*8+3)
    vfloat4 b0 = a0, b1 = a0, b2 = a0, b3 = a0;  // high half

    int j = 0;
    for (; j + 4 <= m; j += 4) {
        int r0 = __builtin_nontemporal_load(sp + j + 0);
        int r1 = __builtin_nontemporal_load(sp + j + 1);
        int r2 = __builtin_nontemporal_load(sp + j + 2);
        int r3 = __builtin_nontemporal_load(sp + j + 3);
        uint4 v0 = xb4[(size_t)r0 * 16 + q];
        uint4 v1 = xb4[(size_t)r1 * 16 + q];
        uint4 v2 = xb4[(size_t)r2 * 16 + q];
        uint4 v3 = xb4[(size_t)r3 * 16 + q];
        float w0 = rsqrtf((float)cursor[r0] + 1.0f);
        float w1 = rsqrtf((float)cursor[r1] + 1.0f);
        float w2 = rsqrtf((float)cursor[r2] + 1.0f);
        float w3 = rsqrtf((float)cursor[r3] + 1.0f);
        a0 += w0 * bf2f4(v0.x, v0.y);  b0 += w0 * bf2f4(v0.z, v0.w);
        a1 += w1 * bf2f4(v1.x, v1.y);  b1 += w1 * bf2f4(v1.z, v1.w);
        a2 += w2 * bf2f4(v2.x, v2.y);  b2 += w2 * bf2f4(v2.z, v2.w);
        a3 += w3 * bf2f4(v3.x, v3.y);  b3 += w3 * bf2f4(v3.z, v3.w);
    }
    for (; j < m; ++j) {
        int r = __builtin_nontemporal_load(sp + j);
        uint4 v = xb4[(size_t)r * 16 + q];
        float w = rsqrtf((float)cursor[r] + 1.0f);
        a0 += w * bf2f4(v.x, v.y);
        b0 += w * bf2f4(v.z, v.w);
    }

    // Overflow edges (normally zero): scan the tiny spill list.
    if (cnt > WMAX) {
        int sc = min(*spillCnt, SPILL_MAX);
        for (int s = 0; s < sc; ++s) {
            int2 pr = spill[s];
            if (pr.y == node) {
                float w = rsqrtf((float)cursor[pr.x] + 1.0f);
                uint4 v = xb4[(size_t)pr.x * 16 + q];
                a0 += w * bf2f4(v.x, v.y);
                b0 += w * bf2f4(v.z, v.w);
            }
        }
    }

    float dc = rsqrtf((float)cnt + 1.0f);
    uint4 xc = xb4[(size_t)node * 16 + q];
    vfloat4 xcl = bf2f4(xc.x, xc.y);
    vfloat4 xch = bf2f4(xc.z, xc.w);
    const vfloat4* bias4 = reinterpret_cast<const vfloat4*>(bias);
    vfloat4 bvl = bias4[q * 2];
    vfloat4 bvh = bias4[q * 2 + 1];
    vfloat4 ovl = bvl + dc * (a0 + a1 + a2 + a3 + dc * xcl);
    vfloat4 ovh = bvh + dc * (b0 + b1 + b2 + b3 + dc * xch);

    vfloat4* out4 = reinterpret_cast<vfloat4*>(out);
    __builtin_nontemporal_store(ovl, out4 + (size_t)node * 32 + q * 2);
    __builtin_nontemporal_store(ovh, out4 + (size_t)node * 32 + q * 2 + 1);
}

// ======================= fallback: round-4 CSR pipeline =======================

__global__ void k_zero(int* __restrict__ degInt, int n) {
    int i = blockIdx.x * blockDim.x + threadIdx.x;
    if (i < n) degInt[i] = 0;
}

__global__ void k_count(const int* __restrict__ col, int* __restrict__ degInt, int e) {
    int i = blockIdx.x * blockDim.x + threadIdx.x;
    if (i < e) atomicAdd(&degInt[col[i]], 1);
}

__global__ void k_scan1(const int* __restrict__ degInt, int* __restrict__ off,
                        int* __restrict__ bsum, int n) {
    __shared__ int sm[B];
    int i = blockIdx.x * B + threadIdx.x;
    int v = (i < n) ? degInt[i] : 0;
    sm[threadIdx.x] = v;
    __syncthreads();
    for (int s = 1; s < B; s <<= 1) {
        int t = (threadIdx.x >= (unsigned)s) ? sm[threadIdx.x - s] : 0;
        __syncthreads();
        sm[threadIdx.x] += t;
        __syncthreads();
    }
    if (i < n) off[i] = sm[threadIdx.x] - v;
    if (threadIdx.x == B - 1) bsum[blockIdx.x] = sm[B - 1];
}

__global__ void k_scan2(int* __restrict__ bsum, int nb) {
    __shared__ int sm[B];
    int v = (threadIdx.x < (unsigned)nb) ? bsum[threadIdx.x] : 0;
    sm[threadIdx.x] = v;
    __syncthreads();
    for (int s = 1; s < B; s <<= 1) {
        int t = (threadIdx.x >= (unsigned)s) ? sm[threadIdx.x - s] : 0;
        __syncthreads();
        sm[threadIdx.x] += t;
        __syncthreads();
    }
    if (threadIdx.x < (unsigned)nb) bsum[threadIdx.x] = sm[threadIdx.x] - v;
}

__global__ void k_scan3(int* __restrict__ off, const int* __restrict__ bsum,
                        const int* __restrict__ degInt, float* __restrict__ dis,
                        int* __restrict__ cursor, int n, int e) {
    int i = blockIdx.x * B + threadIdx.x;
    if (i < n) {
        int o = off[i] + bsum[blockIdx.x];
        off[i] = o;
        cursor[i] = o;
        dis[i] = rsqrtf((float)degInt[i] + 1.0f);
    }
    if (i == 0) off[n] = e;
}

__global__ void k_place_pairs(const int* __restrict__ row, const int* __restrict__ col,
                              const float* __restrict__ dis, int* __restrict__ cursor,
                              int2* __restrict__ pairs, int e) {
    int i = blockIdx.x * blockDim.x + threadIdx.x;
    if (i >= e) return;
    int r = row[i];
    int c = col[i];
    float w = dis[r];
    int pos = atomicAdd(&cursor[c], 1);
    pairs[pos] = make_int2(r, __float_as_int(w));
}

__global__ void k_aggregate_pairs(const float* __restrict__ x, const float* __restrict__ bias,
                                  const float* __restrict__ dis, const int* __restrict__ off,
                                  const int2* __restrict__ pairs, float* __restrict__ out,
                                  float* __restrict__ out2, int n) {
    int gid = blockIdx.x * blockDim.x + threadIdx.x;
    if (gid >= n * 32) return;
    int node = gid >> 5;
    int q    = gid & 31;
    const vfloat4* x4 = reinterpret_cast<const vfloat4*>(x);
    int j   = off[node];
    int end = off[node + 1];
    vfloat4 a0 = {0.f, 0.f, 0.f, 0.f};
    vfloat4 a1 = a0, a2 = a0, a3 = a0;
    for (; j + 4 <= end; j += 4) {
        int2 p0 = pairs[j + 0];
        int2 p1 = pairs[j + 1];
        int2 p2 = pairs[j + 2];
        int2 p3 = pairs[j + 3];
        vfloat4 v0 = x4[(size_t)p0.x * 32 + q];
        vfloat4 v1 = x4[(size_t)p1.x * 32 + q];
        vfloat4 v2 = x4[(size_t)p2.x * 32 + q];
        vfloat4 v3 = x4[(size_t)p3.x * 32 + q];
        a0 += __int_as_float(p0.y) * v0;
        a1 += __int_as_float(p1.y) * v1;
        a2 += __int_as_float(p2.y) * v2;
        a3 += __int_as_float(p3.y) * v3;
    }
    for (; j < end; ++j) {
        int2 p = pairs[j];
        a0 += __int_as_float(p.y) * x4[(size_t)p.x * 32 + q];
    }
    float dc = dis[node];
    vfloat4 xc = x4[(size_t)node * 32 + q];
    vfloat4 bv = reinterpret_cast<const vfloat4*>(bias)[q];
    vfloat4 ov = bv + dc * (a0 + a1 + a2 + a3 + dc * xc);
    __builtin_nontemporal_store(ov, reinterpret_cast<vfloat4*>(out)  + (size_t)node * 32 + q);
    __builtin_nontemporal_store(xc, reinterpret_cast<vfloat4*>(out2) + (size_t)node * 32 + q);
}

// =============================================================================

extern "C" void kernel_launch(void* const* d_in, const int* in_sizes, int n_in,
                              void* d_out, int out_size, void* d_ws, size_t ws_size,
                              hipStream_t stream) {
    const float* x    = (const float*)d_in[0];
    const int*   idx  = (const int*)d_in[1];   // [2, E]
    const float* bias = (const float*)d_in[2];

    const int n = in_sizes[0] / D;             // 50000
    const int e = in_sizes[1] / 2;             // 600000

    const int* row = idx;                      // sources
    const int* col = idx + e;                  // destinations

    float* out  = (float*)d_out;                     // [n, 128]
    float* out2 = (float*)d_out + (size_t)n * D;     // init_embeds

    const int nbN = (n + B - 1) / B;
    const int nbE = (e + B - 1) / B;
    const int prepB = (n * 32 + B - 1) / B;
    const int nBlocksA = (e + CH - 1) / CH;

    // ---- ELL + bf16 + bucket layout ----
    char* p0 = (char*)d_ws;
    int*  cursor  = (int*)p0;                        p0 += (size_t)n * 4;
    int*  spillCnt= (int*)p0;                        p0 += 16;
    int2* spill   = (int2*)p0;                       p0 += (size_t)SPILL_MAX * 8;
    p0 = (char*)(((uintptr_t)p0 + 15) & ~(uintptr_t)15);
    uint2* xb     = (uint2*)p0;                      p0 += (size_t)n * 32 * 8;      // bf16 x
    int*  ssrc    = (int*)p0;                        p0 += (size_t)n * WMAX * 4;
    p0 = (char*)(((uintptr_t)p0 + 15) & ~(uintptr_t)15);
    long long* bkt = (long long*)p0;                 p0 += (size_t)NPART * nBlocksA * CH * 8;
    int*  cnt     = (int*)p0;                        p0 += (size_t)nBlocksA * NPART * 4;
    size_t need_ell = (size_t)(p0 - (char*)d_ws);

    if (ws_size >= need_ell) {
        const int plB = 2048;   // 8 XCD groups x 256 blocks, all co-resident
        int maxPart = 0;
        for (int p = 0; p < NPART; ++p) {
            int lo = (int)((long long)n * p / NPART);
            int hi = (int)((long long)n * (p + 1) / NPART);
            if (hi - lo > maxPart) maxPart = hi - lo;
        }
        const int bpg = (maxPart + 15) / 16;           // 16 nodes per block
        const int agB = bpg * NPART;
        k_prep  <<<prepB,    B, 0, stream>>>(x, out2, xb, cursor, spillCnt, n);
        k_bucket<<<nBlocksA, B, 0, stream>>>(row, col, bkt, cnt, e, n, nBlocksA);
        k_place2<<<plB,      B, 0, stream>>>(bkt, cnt, cursor, ssrc, spill, spillCnt, nBlocksA);
        k_agg_ell<<<agB,     B, 0, stream>>>(xb, bias, cursor, ssrc, spill, spillCnt, out, n);
        return;
    }

    // ---- fallback: round-4 CSR pipeline ----
    char* p = (char*)d_ws;
    int*   degInt = (int*)p;            p += (size_t)n * 4;
    int*   cur2   = (int*)p;            p += (size_t)n * 4;
    int*   off    = (int*)p;            p += (size_t)(n + 1) * 4;
    int*   bsum   = (int*)p;            p += 256 * 4;
    float* dis    = (float*)p;          p += (size_t)n * 4;
    p = (char*)(((uintptr_t)p + 15) & ~(uintptr_t)15);
    int2*  pairs  = (int2*)p;

    const int aggB = (n * 32 + B - 1) / B;
    k_zero <<<nbN, B, 0, stream>>>(degInt, n);
    k_count<<<nbE, B, 0, stream>>>(col, degInt, e);
    k_scan1<<<nbN, B, 0, stream>>>(degInt, off, bsum, n);
    k_scan2<<<1,   B, 0, stream>>>(bsum, nbN);
    k_scan3<<<nbN, B, 0, stream>>>(off, bsum, degInt, dis, cur2, n, e);
    k_place_pairs<<<nbE, B, 0, stream>>>(row, col, dis, cur2, pairs, e);
    k_aggregate_pairs<<<aggB, B, 0, stream>>>(x, bias, dis, off, pairs, out, out2, n);
}